// Round 12
// baseline (576.598 us; speedup 1.0000x reference)
//
#include <hip/hip_runtime.h>
#include <hip/hip_bf16.h>

// DKVMN forward. B=256 S=512 M=128 DK=128 DV=256 FC=128.
// Chunked over time (TC=256 -> NC=2). Per chunk (order matters):
//   k2 (bf16 MFMA): {-e|a} = act(qa @ [We|Wa]^T), stored INTERLEAVED bf16x2 per d
//   k1 (bf16 MFMA): w = softmax(qe @ MK^T)
//   k3: sequential read/update; 1024 blocks (XCD-affine: b=bid&255, dq=bid>>8)
//       x 512 thr (8 mq-waves, 16 m each); w via scalar s_load depth-4 SGPR
//       pipeline; ea via 16-step-deep rotating VGPR pipeline; op_sel gate-fma;
//       G=16 batches, 2 barriers per 16 steps.
//   k4 (bf16 MFMA): logits = Wp @ tanh(Wr @ [read|qe])

#define BB    256
#define SS    512
#define MM    128
#define DKk   128
#define DVv   256

typedef float  f32x2  __attribute__((ext_vector_type(2)));
typedef float  f32x4  __attribute__((ext_vector_type(4)));
typedef short  bf16x8 __attribute__((ext_vector_type(8)));

static __device__ __forceinline__ unsigned short f2bf(float f) {
    unsigned u = __float_as_uint(f);
    unsigned r = (u + 0x7FFFu + ((u >> 16) & 1u)) >> 16;
    return (unsigned short)r;
}
static __device__ __forceinline__ float fast_tanh(float x) {
    float ex = __expf(2.f * x);
    return 1.f - 2.f / (ex + 1.f);
}
static __device__ __forceinline__ float fast_sigmoid(float x) {
    return 1.f / (1.f + __expf(-x));
}

// ---------------------------------------------------------------- convert tables to bf16
__global__ __launch_bounds__(256) void kcvt(const float* __restrict__ qa_tab,
                                            const float* __restrict__ q_tab,
                                            const float* __restrict__ W_er,
                                            const float* __restrict__ W_ad,
                                            const float* __restrict__ W_rd,
                                            const float* __restrict__ mk,
                                            unsigned short* __restrict__ qa16,
                                            unsigned short* __restrict__ q16,
                                            unsigned short* __restrict__ wea16,
                                            unsigned short* __restrict__ wrd16,
                                            unsigned short* __restrict__ mk16,
                                            int n_qa, int n_q) {
    for (int i = blockIdx.x * 256 + threadIdx.x; i < n_qa; i += gridDim.x * 256)
        qa16[i] = f2bf(qa_tab[i]);
    for (int i = blockIdx.x * 256 + threadIdx.x; i < n_q; i += gridDim.x * 256)
        q16[i] = f2bf(q_tab[i]);
    for (int i = blockIdx.x * 256 + threadIdx.x; i < 65536; i += gridDim.x * 256) {
        wea16[i] = f2bf(W_er[i]);
        wea16[65536 + i] = f2bf(W_ad[i]);
    }
    for (int i = blockIdx.x * 256 + threadIdx.x; i < 49152; i += gridDim.x * 256)
        wrd16[i] = f2bf(W_rd[i]);
    for (int i = blockIdx.x * 256 + threadIdx.x; i < 16384; i += gridDim.x * 256)
        mk16[i] = f2bf(mk[i]);
}

// ---------------------------------------------------------------- k1: w = softmax(qe @ MK^T) via bf16 MFMA
__global__ __launch_bounds__(256) void k1_mfma(const int* __restrict__ q_data,
                                               const unsigned short* __restrict__ q16,
                                               const unsigned short* __restrict__ mk16,
                                               float* __restrict__ w_buf,
                                               int tcs, int tcm, int coff) {
    __shared__ __align__(16) unsigned short A_lds[128 * 64];
    __shared__ int qidx[128];
    int t = threadIdx.x;
    int row0 = blockIdx.x * 128;
    if (t < 128) {
        int rl = row0 + t;
        qidx[t] = q_data[(rl >> tcs) * SS + coff + (rl & tcm)];
    }
    int l = t & 63;
    int wid = t >> 6;
    f32x4 acc[2][8];
    #pragma unroll
    for (int i = 0; i < 2; ++i)
        #pragma unroll
        for (int j = 0; j < 8; ++j)
            acc[i][j] = (f32x4){0.f, 0.f, 0.f, 0.f};

    for (int ks = 0; ks < 128; ks += 64) {
        __syncthreads();
        #pragma unroll
        for (int p = 0; p < 4; ++p) {
            int U = p * 256 + t;
            int r = U >> 3, kb = U & 7;
            int kb_log = kb ^ (r & 7);
            int4 v = *reinterpret_cast<const int4*>(q16 + (size_t)qidx[r] * DKk + ks + kb_log * 8);
            *reinterpret_cast<int4*>(&A_lds[U * 8]) = v;
        }
        __syncthreads();
        #pragma unroll
        for (int ksub = 0; ksub < 2; ++ksub) {
            bf16x8 af[2];
            #pragma unroll
            for (int mi = 0; mi < 2; ++mi) {
                int r = wid * 32 + mi * 16 + (l & 15);
                int kb_log = ksub * 4 + (l >> 4);
                int pu = r * 8 + (kb_log ^ (r & 7));
                af[mi] = *reinterpret_cast<const bf16x8*>(&A_lds[pu * 8]);
            }
            #pragma unroll
            for (int nj = 0; nj < 8; ++nj) {
                int col = nj * 16 + (l & 15);
                bf16x8 bf = *reinterpret_cast<const bf16x8*>(
                    mk16 + (size_t)col * DKk + ks + ksub * 32 + (l >> 4) * 8);
                #pragma unroll
                for (int mi = 0; mi < 2; ++mi)
                    acc[mi][nj] = __builtin_amdgcn_mfma_f32_16x16x32_bf16(af[mi], bf, acc[mi][nj], 0, 0, 0);
            }
        }
    }
    #pragma unroll
    for (int mi = 0; mi < 2; ++mi) {
        #pragma unroll
        for (int reg = 0; reg < 4; ++reg) {
            float mx = acc[mi][0][reg];
            #pragma unroll
            for (int nj = 1; nj < 8; ++nj) mx = fmaxf(mx, acc[mi][nj][reg]);
            #pragma unroll
            for (int off = 1; off < 16; off <<= 1) mx = fmaxf(mx, __shfl_xor(mx, off, 64));
            float p[8], s = 0.f;
            #pragma unroll
            for (int nj = 0; nj < 8; ++nj) { p[nj] = __expf(acc[mi][nj][reg] - mx); s += p[nj]; }
            #pragma unroll
            for (int off = 1; off < 16; off <<= 1) s += __shfl_xor(s, off, 64);
            float inv = 1.f / s;
            int row = row0 + wid * 32 + mi * 16 + (l >> 4) * 4 + reg;
            #pragma unroll
            for (int nj = 0; nj < 8; ++nj)
                w_buf[(size_t)row * MM + nj * 16 + (l & 15)] = p[nj] * inv;
        }
    }
}

// ---------------------------------------------------------------- k2: {-e|a} via bf16 MFMA, interleaved bf16x2 out
__global__ __launch_bounds__(256) void k2_ea_mfma(const int* __restrict__ qa_data,
                                                  const unsigned short* __restrict__ qa16,
                                                  const unsigned short* __restrict__ wea16,
                                                  const float* __restrict__ b_er,
                                                  const float* __restrict__ b_ad,
                                                  unsigned short* __restrict__ ea16,
                                                  int tcs, int tcm, int coff) {
    __shared__ __align__(16) unsigned short A_lds[128 * 64];
    __shared__ int qidx[128];
    int t = threadIdx.x;
    int rb = blockIdx.x >> 2, cb = blockIdx.x & 3;
    int row0 = rb * 128;
    if (t < 128) {
        int rl = row0 + t;
        qidx[t] = qa_data[(rl >> tcs) * SS + coff + (rl & tcm)];
    }
    int l = t & 63;
    int wid = t >> 6, wr = wid >> 1, wc = wid & 1;
    f32x4 acc[4][4];
    #pragma unroll
    for (int i = 0; i < 4; ++i)
        #pragma unroll
        for (int j = 0; j < 4; ++j)
            acc[i][j] = (f32x4){0.f, 0.f, 0.f, 0.f};

    for (int ks = 0; ks < 256; ks += 64) {
        __syncthreads();
        #pragma unroll
        for (int p = 0; p < 4; ++p) {
            int U = p * 256 + t;
            int r = U >> 3, kb = U & 7;
            int kb_log = kb ^ (r & 7);
            int4 v = *reinterpret_cast<const int4*>(qa16 + (size_t)qidx[r] * 256 + ks + kb_log * 8);
            *reinterpret_cast<int4*>(&A_lds[U * 8]) = v;
        }
        __syncthreads();
        #pragma unroll
        for (int ksub = 0; ksub < 2; ++ksub) {
            bf16x8 af[4];
            #pragma unroll
            for (int mi = 0; mi < 4; ++mi) {
                int r = wr * 64 + mi * 16 + (l & 15);
                int kb_log = ksub * 4 + (l >> 4);
                int pu = r * 8 + (kb_log ^ (r & 7));
                af[mi] = *reinterpret_cast<const bf16x8*>(&A_lds[pu * 8]);
            }
            #pragma unroll
            for (int nj = 0; nj < 4; ++nj) {
                int col = cb * 128 + wc * 64 + nj * 16 + (l & 15);
                bf16x8 bf = *reinterpret_cast<const bf16x8*>(
                    wea16 + (size_t)col * 256 + ks + ksub * 32 + (l >> 4) * 8);
                #pragma unroll
                for (int mi = 0; mi < 4; ++mi)
                    acc[mi][nj] = __builtin_amdgcn_mfma_f32_16x16x32_bf16(af[mi], bf, acc[mi][nj], 0, 0, 0);
            }
        }
    }
    // epilogue: interleaved store — row stride 512 shorts; slot 2*d = -e, 2*d+1 = a
    #pragma unroll
    for (int nj = 0; nj < 4; ++nj) {
        int col = cb * 128 + wc * 64 + nj * 16 + (l & 15);
        bool is_e = (cb < 2);
        float bias = is_e ? b_er[col] : b_ad[col - 256];
        #pragma unroll
        for (int mi = 0; mi < 4; ++mi) {
            #pragma unroll
            for (int reg = 0; reg < 4; ++reg) {
                int rl = row0 + wr * 64 + mi * 16 + (l >> 4) * 4 + reg;
                float x = acc[mi][nj][reg] + bias;
                float y = is_e ? -fast_sigmoid(x) : fast_tanh(x);
                int idx = is_e ? (2 * col) : (2 * (col - 256) + 1);
                ea16[(size_t)rl * 512 + idx] = f2bf(y);
            }
        }
    }
}

// ---------------------------------------------------------------- k3: sequential read/update
// grid = 4*BB blocks; XCD-affine decode: b = bid&255, dq = bid>>8 (same-b blocks
// share an XCD -> w fetched once per b). 512 thr = 8 mq-waves x 16 m; lane = d.
// w: scalar s_load depth-4 (wA..wD). ea: rotating 16-deep VGPR pipeline (uc[G]
// reloaded for batch t0+16 right after its last use). op_sel gate-fma.
__global__ __launch_bounds__(512, 8) void k3_seq(const float* __restrict__ w_buf,
                                                 const unsigned short* __restrict__ ea16,
                                                 const float* __restrict__ init_mem,
                                                 float* __restrict__ state,
                                                 unsigned short* __restrict__ reads16,
                                                 int TC, int first, int last) {
    __shared__ float rdlds[16][8][64];
    int tid = threadIdx.x;
    int mq = tid >> 6, lane = tid & 63;
    int b  = blockIdx.x & (BB - 1);
    int dq = blockIdx.x >> 8;
    int d  = dq * 64 + lane;
    int m0 = mq * 16;
    f32x2 mem[8];
    if (first) {
        #pragma unroll
        for (int i = 0; i < 8; ++i) {
            mem[i].x = init_mem[(size_t)(m0 + 2 * i) * DVv + d];
            mem[i].y = init_mem[(size_t)(m0 + 2 * i + 1) * DVv + d];
        }
    } else {
        #pragma unroll
        for (int i = 0; i < 8; ++i)
            mem[i] = *reinterpret_cast<const f32x2*>(&state[((size_t)b * DVv + d) * MM + m0 + 2 * i]);
    }
    size_t rb = (size_t)b * TC;
    const unsigned* ea32 = reinterpret_cast<const unsigned*>(ea16);
    unsigned wrow = (unsigned)__builtin_amdgcn_readfirstlane((int)((unsigned)(rb * MM) + m0));
    const f32x2* wbase2 = reinterpret_cast<const f32x2*>(w_buf + wrow);
    int tcl = TC - 1;

    f32x2 wA[8], wB[8], wC[8], wD[8];
    #define WLOAD(W, T)                                                             \
    {                                                                               \
        _Pragma("unroll")                                                           \
        for (int j = 0; j < 8; ++j) W[j] = wbase2[(size_t)(T) * 64 + j];            \
    }
    WLOAD(wA, 0) WLOAD(wB, 1) WLOAD(wC, 2) WLOAD(wD, 3)

    unsigned uc[16];
    #pragma unroll
    for (int g = 0; g < 16; ++g)
        uc[g] = ea32[(rb + g) * 256 + d];

    for (int t0 = 0; t0 < TC; t0 += 16) {
        int tnb = t0 + 16;                 // next batch base (clamped per-step)
        #define K3_STEP(G, WCUR)                                                              \
        {                                                                                     \
            f32x2 EA;                                                                         \
            EA.x = __uint_as_float(uc[G] << 16);            /* -e */                          \
            EA.y = __uint_as_float(uc[G] & 0xffff0000u);    /*  a */                          \
            f32x2 rd; rd.x = 0.f; rd.y = 0.f;                                                 \
            _Pragma("unroll")                                                                 \
            for (int i = 0; i < 8; ++i) {                                                     \
                f32x2 tt;                                                                     \
                asm("v_pk_fma_f32 %0, %1, %2, %0" : "+v"(rd) : "s"(WCUR[i]), "v"(mem[i]));    \
                asm("v_pk_fma_f32 %0, %1, %2, %1 op_sel:[0,0,1] op_sel_hi:[0,1,1]"            \
                    : "=v"(tt) : "v"(EA), "v"(mem[i]));                                       \
                asm("v_pk_fma_f32 %0, %1, %2, %0" : "+v"(mem[i]) : "s"(WCUR[i]), "v"(tt));    \
            }                                                                                 \
            rdlds[G][mq][lane] = rd.x + rd.y;                                                 \
            int tp = t0 + G + 4; tp = (tp < tcl) ? tp : tcl;                                  \
            WLOAD(WCUR, tp)                                                                   \
            int te = tnb + G; te = (te < tcl) ? te : tcl;                                     \
            uc[G] = ea32[(rb + te) * 256 + d];                                                \
        }
        K3_STEP(0,  wA) K3_STEP(1,  wB) K3_STEP(2,  wC) K3_STEP(3,  wD)
        K3_STEP(4,  wA) K3_STEP(5,  wB) K3_STEP(6,  wC) K3_STEP(7,  wD)
        K3_STEP(8,  wA) K3_STEP(9,  wB) K3_STEP(10, wC) K3_STEP(11, wD)
        K3_STEP(12, wA) K3_STEP(13, wB) K3_STEP(14, wC) K3_STEP(15, wD)
        #undef K3_STEP
        __syncthreads();
        #pragma unroll
        for (int r = 0; r < 2; ++r) {
            int idx = tid + r * 512;
            int g = idx >> 6, dl = idx & 63;
            float s = rdlds[g][0][dl] + rdlds[g][1][dl] + rdlds[g][2][dl] + rdlds[g][3][dl]
                    + rdlds[g][4][dl] + rdlds[g][5][dl] + rdlds[g][6][dl] + rdlds[g][7][dl];
            reads16[(rb + t0 + g) * DVv + dq * 64 + dl] = f2bf(s);
        }
        __syncthreads();
    }
    #undef WLOAD
    if (!last) {
        #pragma unroll
        for (int i = 0; i < 8; ++i)
            *reinterpret_cast<f32x2*>(&state[((size_t)b * DVv + d) * MM + m0 + 2 * i]) = mem[i];
    }
}

// ---------------------------------------------------------------- k4: logits via bf16 MFMA
__global__ __launch_bounds__(256) void k4_mfma(const int* __restrict__ q_data,
                                               const unsigned short* __restrict__ q16,
                                               const unsigned short* __restrict__ reads16,
                                               const unsigned short* __restrict__ wrd16,
                                               const float* __restrict__ b_rd,
                                               const float* __restrict__ W_pr,
                                               const float* __restrict__ b_pr,
                                               float* __restrict__ out,
                                               int tcs, int tcm, int coff) {
    __shared__ __align__(16) unsigned short A_lds[128 * 64];
    __shared__ int qidx[128];
    __shared__ float plds[2][128];
    int t = threadIdx.x;
    int row0 = blockIdx.x * 128;
    if (t < 128) {
        int rl = row0 + t;
        qidx[t] = q_data[(rl >> tcs) * SS + coff + (rl & tcm)];
    }
    int l = t & 63;
    int wid = t >> 6, wr = wid >> 1, wc = wid & 1;
    f32x4 acc[4][4];
    #pragma unroll
    for (int i = 0; i < 4; ++i)
        #pragma unroll
        for (int j = 0; j < 4; ++j)
            acc[i][j] = (f32x4){0.f, 0.f, 0.f, 0.f};

    for (int ks = 0; ks < 384; ks += 64) {
        __syncthreads();
        #pragma unroll
        for (int p = 0; p < 4; ++p) {
            int U = p * 256 + t;
            int r = U >> 3, kb = U & 7;
            int kb_log = kb ^ (r & 7);
            int kg = ks + kb_log * 8;
            const unsigned short* src = (kg < 256)
                ? (reads16 + (size_t)(row0 + r) * DVv + kg)
                : (q16 + (size_t)qidx[r] * DKk + (kg - 256));
            int4 v = *reinterpret_cast<const int4*>(src);
            *reinterpret_cast<int4*>(&A_lds[U * 8]) = v;
        }
        __syncthreads();
        #pragma unroll
        for (int ksub = 0; ksub < 2; ++ksub) {
            bf16x8 af[4];
            #pragma unroll
            for (int mi = 0; mi < 4; ++mi) {
                int r = wr * 64 + mi * 16 + (l & 15);
                int kb_log = ksub * 4 + (l >> 4);
                int pu = r * 8 + (kb_log ^ (r & 7));
                af[mi] = *reinterpret_cast<const bf16x8*>(&A_lds[pu * 8]);
            }
            #pragma unroll
            for (int nj = 0; nj < 4; ++nj) {
                int col = wc * 64 + nj * 16 + (l & 15);
                bf16x8 bf = *reinterpret_cast<const bf16x8*>(
                    wrd16 + (size_t)col * 384 + ks + ksub * 32 + (l >> 4) * 8);
                #pragma unroll
                for (int mi = 0; mi < 4; ++mi)
                    acc[mi][nj] = __builtin_amdgcn_mfma_f32_16x16x32_bf16(af[mi], bf, acc[mi][nj], 0, 0, 0);
            }
        }
    }
    float part[16];
    #pragma unroll
    for (int k = 0; k < 16; ++k) part[k] = 0.f;
    #pragma unroll
    for (int nj = 0; nj < 4; ++nj) {
        int col = wc * 64 + nj * 16 + (l & 15);
        float bias = b_rd[col];
        float wpr = W_pr[col];
        #pragma unroll
        for (int mi = 0; mi < 4; ++mi) {
            #pragma unroll
            for (int reg = 0; reg < 4; ++reg) {
                float h = fast_tanh(acc[mi][nj][reg] + bias);
                part[mi * 4 + reg] = fmaf(h, wpr, part[mi * 4 + reg]);
            }
        }
    }
    #pragma unroll
    for (int k = 0; k < 16; ++k) {
        #pragma unroll
        for (int off = 1; off < 16; off <<= 1)
            part[k] += __shfl_xor(part[k], off, 64);
    }
    if ((l & 15) == 0) {
        #pragma unroll
        for (int mi = 0; mi < 4; ++mi)
            #pragma unroll
            for (int reg = 0; reg < 4; ++reg) {
                int row = wr * 64 + mi * 16 + (l >> 4) * 4 + reg;
                plds[wc][row] = part[mi * 4 + reg];
            }
    }
    __syncthreads();
    if (t < 128) {
        float s = plds[0][t] + plds[1][t] + b_pr[0];
        int rl = row0 + t;
        out[(rl >> tcs) * SS + coff + (rl & tcm)] = s;
    }
}

// ---------------------------------------------------------------- launch
extern "C" void kernel_launch(void* const* d_in, const int* in_sizes, int n_in,
                              void* d_out, int out_size, void* d_ws, size_t ws_size,
                              hipStream_t stream) {
    const int*   q_data   = (const int*)d_in[0];
    const int*   qa_data  = (const int*)d_in[1];
    const float* q_tab    = (const float*)d_in[2];
    const float* qa_tab   = (const float*)d_in[3];
    const float* mk       = (const float*)d_in[4];
    const float* init_mem = (const float*)d_in[5];
    const float* W_er     = (const float*)d_in[6];
    const float* b_er     = (const float*)d_in[7];
    const float* W_ad     = (const float*)d_in[8];
    const float* b_ad     = (const float*)d_in[9];
    const float* W_rd     = (const float*)d_in[10];
    const float* b_rd     = (const float*)d_in[11];
    const float* W_pr     = (const float*)d_in[12];
    const float* b_pr     = (const float*)d_in[13];
    float* out = (float*)d_out;

    const size_t state_f = (size_t)BB * MM * DVv;          // 8,388,608 floats
    const size_t qa16_n  = (size_t)in_sizes[3];            // 20001*256 ushorts
    const size_t q16_n   = (size_t)in_sizes[2];            // 10001*128 ushorts
    const size_t wea16_n = 131072;
    const size_t wrd16_n = 49152;
    const size_t mk16_n  = 16384;
    const size_t bf16_f  = (qa16_n + q16_n + wea16_n + wrd16_n + mk16_n) / 2 + 32;

    size_t avail_f = ws_size / 4;
    int TC = 16;
    {
        const int cand[] = {256, 128, 64, 32, 16};
        for (int i = 0; i < 5; ++i) {
            size_t need = state_f + bf16_f + (size_t)BB * cand[i] * (MM + 256 + 128);
            if (need <= avail_f) { TC = cand[i]; break; }
        }
    }
    int NC = SS / TC;
    int tcs = __builtin_ctz(TC);
    int tcm = TC - 1;

    float* ws      = (float*)d_ws;
    float* state   = ws;
    float* w_buf   = state + state_f;                          // B*TC*128 f32
    unsigned short* ea16    = (unsigned short*)(w_buf + (size_t)BB * TC * MM);   // B*TC*512 us
    unsigned short* reads16 = ea16 + (size_t)BB * TC * 512;                      // B*TC*256 us
    unsigned short* qa16  = reads16 + (size_t)BB * TC * DVv;
    unsigned short* q16   = qa16 + qa16_n;
    unsigned short* wea16 = q16 + q16_n;
    unsigned short* wrd16 = wea16 + wea16_n;
    unsigned short* mk16  = wrd16 + wrd16_n;

    kcvt<<<1024, 256, 0, stream>>>(qa_tab, q_tab, W_er, W_ad, W_rd, mk,
                                   qa16, q16, wea16, wrd16, mk16,
                                   (int)qa16_n, (int)q16_n);
    for (int c = 0; c < NC; ++c) {
        int coff = c * TC;
        int rows = BB * TC;
        // k2 first, then k1 (so w_buf is freshly written / L2-warm when k3 reads it)
        k2_ea_mfma<<<(rows / 128) * 4, 256, 0, stream>>>(qa_data, qa16, wea16, b_er, b_ad,
                                                         ea16, tcs, tcm, coff);
        k1_mfma<<<rows / 128, 256, 0, stream>>>(q_data, q16, mk16, w_buf, tcs, tcm, coff);
        k3_seq<<<4 * BB, 512, 0, stream>>>(w_buf, ea16, init_mem, state, reads16,
                                           TC, c == 0, c == NC - 1);
        k4_mfma<<<rows / 128, 256, 0, stream>>>(q_data, q16, reads16, wrd16, b_rd, W_pr, b_pr,
                                                out, tcs, tcm, coff);
    }
}

// Round 13
// 561.587 us; speedup vs baseline: 1.0267x; 1.0267x over previous
//
#include <hip/hip_runtime.h>
#include <hip/hip_bf16.h>

// DKVMN forward. B=256 S=512 M=128 DK=128 DV=256 FC=128.
// Chunked over time (TC=256 -> NC=2). Per chunk (order matters):
//   k2 (bf16 MFMA): {-e|a} = act(qa @ [We|Wa]^T), stored INTERLEAVED bf16x2 per d
//   k1 (bf16 MFMA): w = softmax(qe @ MK^T)
//   k3: sequential read/update; 1024 blocks (XCD-affine: b=bid&255, dq=bid>>8)
//       x 512 thr (8 mq-waves, 16 m each); w via scalar s_load depth-4 SGPR
//       pipeline (clamps on scalar pipe); ea via double-buffered batch-of-8
//       VGPR prefetch (full 8-step latency window, batch-level addressing);
//       op_sel gate-fma; G=8 LDS combine.
//   k4 (bf16 MFMA): logits = Wp @ tanh(Wr @ [read|qe])

#define BB    256
#define SS    512
#define MM    128
#define DKk   128
#define DVv   256

typedef float  f32x2  __attribute__((ext_vector_type(2)));
typedef float  f32x4  __attribute__((ext_vector_type(4)));
typedef short  bf16x8 __attribute__((ext_vector_type(8)));

static __device__ __forceinline__ unsigned short f2bf(float f) {
    unsigned u = __float_as_uint(f);
    unsigned r = (u + 0x7FFFu + ((u >> 16) & 1u)) >> 16;
    return (unsigned short)r;
}
static __device__ __forceinline__ float fast_tanh(float x) {
    float ex = __expf(2.f * x);
    return 1.f - 2.f / (ex + 1.f);
}
static __device__ __forceinline__ float fast_sigmoid(float x) {
    return 1.f / (1.f + __expf(-x));
}

// ---------------------------------------------------------------- convert tables to bf16
__global__ __launch_bounds__(256) void kcvt(const float* __restrict__ qa_tab,
                                            const float* __restrict__ q_tab,
                                            const float* __restrict__ W_er,
                                            const float* __restrict__ W_ad,
                                            const float* __restrict__ W_rd,
                                            const float* __restrict__ mk,
                                            unsigned short* __restrict__ qa16,
                                            unsigned short* __restrict__ q16,
                                            unsigned short* __restrict__ wea16,
                                            unsigned short* __restrict__ wrd16,
                                            unsigned short* __restrict__ mk16,
                                            int n_qa, int n_q) {
    for (int i = blockIdx.x * 256 + threadIdx.x; i < n_qa; i += gridDim.x * 256)
        qa16[i] = f2bf(qa_tab[i]);
    for (int i = blockIdx.x * 256 + threadIdx.x; i < n_q; i += gridDim.x * 256)
        q16[i] = f2bf(q_tab[i]);
    for (int i = blockIdx.x * 256 + threadIdx.x; i < 65536; i += gridDim.x * 256) {
        wea16[i] = f2bf(W_er[i]);
        wea16[65536 + i] = f2bf(W_ad[i]);
    }
    for (int i = blockIdx.x * 256 + threadIdx.x; i < 49152; i += gridDim.x * 256)
        wrd16[i] = f2bf(W_rd[i]);
    for (int i = blockIdx.x * 256 + threadIdx.x; i < 16384; i += gridDim.x * 256)
        mk16[i] = f2bf(mk[i]);
}

// ---------------------------------------------------------------- k1: w = softmax(qe @ MK^T) via bf16 MFMA
__global__ __launch_bounds__(256) void k1_mfma(const int* __restrict__ q_data,
                                               const unsigned short* __restrict__ q16,
                                               const unsigned short* __restrict__ mk16,
                                               float* __restrict__ w_buf,
                                               int tcs, int tcm, int coff) {
    __shared__ __align__(16) unsigned short A_lds[128 * 64];
    __shared__ int qidx[128];
    int t = threadIdx.x;
    int row0 = blockIdx.x * 128;
    if (t < 128) {
        int rl = row0 + t;
        qidx[t] = q_data[(rl >> tcs) * SS + coff + (rl & tcm)];
    }
    int l = t & 63;
    int wid = t >> 6;
    f32x4 acc[2][8];
    #pragma unroll
    for (int i = 0; i < 2; ++i)
        #pragma unroll
        for (int j = 0; j < 8; ++j)
            acc[i][j] = (f32x4){0.f, 0.f, 0.f, 0.f};

    for (int ks = 0; ks < 128; ks += 64) {
        __syncthreads();
        #pragma unroll
        for (int p = 0; p < 4; ++p) {
            int U = p * 256 + t;
            int r = U >> 3, kb = U & 7;
            int kb_log = kb ^ (r & 7);
            int4 v = *reinterpret_cast<const int4*>(q16 + (size_t)qidx[r] * DKk + ks + kb_log * 8);
            *reinterpret_cast<int4*>(&A_lds[U * 8]) = v;
        }
        __syncthreads();
        #pragma unroll
        for (int ksub = 0; ksub < 2; ++ksub) {
            bf16x8 af[2];
            #pragma unroll
            for (int mi = 0; mi < 2; ++mi) {
                int r = wid * 32 + mi * 16 + (l & 15);
                int kb_log = ksub * 4 + (l >> 4);
                int pu = r * 8 + (kb_log ^ (r & 7));
                af[mi] = *reinterpret_cast<const bf16x8*>(&A_lds[pu * 8]);
            }
            #pragma unroll
            for (int nj = 0; nj < 8; ++nj) {
                int col = nj * 16 + (l & 15);
                bf16x8 bf = *reinterpret_cast<const bf16x8*>(
                    mk16 + (size_t)col * DKk + ks + ksub * 32 + (l >> 4) * 8);
                #pragma unroll
                for (int mi = 0; mi < 2; ++mi)
                    acc[mi][nj] = __builtin_amdgcn_mfma_f32_16x16x32_bf16(af[mi], bf, acc[mi][nj], 0, 0, 0);
            }
        }
    }
    #pragma unroll
    for (int mi = 0; mi < 2; ++mi) {
        #pragma unroll
        for (int reg = 0; reg < 4; ++reg) {
            float mx = acc[mi][0][reg];
            #pragma unroll
            for (int nj = 1; nj < 8; ++nj) mx = fmaxf(mx, acc[mi][nj][reg]);
            #pragma unroll
            for (int off = 1; off < 16; off <<= 1) mx = fmaxf(mx, __shfl_xor(mx, off, 64));
            float p[8], s = 0.f;
            #pragma unroll
            for (int nj = 0; nj < 8; ++nj) { p[nj] = __expf(acc[mi][nj][reg] - mx); s += p[nj]; }
            #pragma unroll
            for (int off = 1; off < 16; off <<= 1) s += __shfl_xor(s, off, 64);
            float inv = 1.f / s;
            int row = row0 + wid * 32 + mi * 16 + (l >> 4) * 4 + reg;
            #pragma unroll
            for (int nj = 0; nj < 8; ++nj)
                w_buf[(size_t)row * MM + nj * 16 + (l & 15)] = p[nj] * inv;
        }
    }
}

// ---------------------------------------------------------------- k2: {-e|a} via bf16 MFMA, interleaved bf16x2 out
__global__ __launch_bounds__(256) void k2_ea_mfma(const int* __restrict__ qa_data,
                                                  const unsigned short* __restrict__ qa16,
                                                  const unsigned short* __restrict__ wea16,
                                                  const float* __restrict__ b_er,
                                                  const float* __restrict__ b_ad,
                                                  unsigned short* __restrict__ ea16,
                                                  int tcs, int tcm, int coff) {
    __shared__ __align__(16) unsigned short A_lds[128 * 64];
    __shared__ int qidx[128];
    int t = threadIdx.x;
    int rb = blockIdx.x >> 2, cb = blockIdx.x & 3;
    int row0 = rb * 128;
    if (t < 128) {
        int rl = row0 + t;
        qidx[t] = qa_data[(rl >> tcs) * SS + coff + (rl & tcm)];
    }
    int l = t & 63;
    int wid = t >> 6, wr = wid >> 1, wc = wid & 1;
    f32x4 acc[4][4];
    #pragma unroll
    for (int i = 0; i < 4; ++i)
        #pragma unroll
        for (int j = 0; j < 4; ++j)
            acc[i][j] = (f32x4){0.f, 0.f, 0.f, 0.f};

    for (int ks = 0; ks < 256; ks += 64) {
        __syncthreads();
        #pragma unroll
        for (int p = 0; p < 4; ++p) {
            int U = p * 256 + t;
            int r = U >> 3, kb = U & 7;
            int kb_log = kb ^ (r & 7);
            int4 v = *reinterpret_cast<const int4*>(qa16 + (size_t)qidx[r] * 256 + ks + kb_log * 8);
            *reinterpret_cast<int4*>(&A_lds[U * 8]) = v;
        }
        __syncthreads();
        #pragma unroll
        for (int ksub = 0; ksub < 2; ++ksub) {
            bf16x8 af[4];
            #pragma unroll
            for (int mi = 0; mi < 4; ++mi) {
                int r = wr * 64 + mi * 16 + (l & 15);
                int kb_log = ksub * 4 + (l >> 4);
                int pu = r * 8 + (kb_log ^ (r & 7));
                af[mi] = *reinterpret_cast<const bf16x8*>(&A_lds[pu * 8]);
            }
            #pragma unroll
            for (int nj = 0; nj < 4; ++nj) {
                int col = cb * 128 + wc * 64 + nj * 16 + (l & 15);
                bf16x8 bf = *reinterpret_cast<const bf16x8*>(
                    wea16 + (size_t)col * 256 + ks + ksub * 32 + (l >> 4) * 8);
                #pragma unroll
                for (int mi = 0; mi < 4; ++mi)
                    acc[mi][nj] = __builtin_amdgcn_mfma_f32_16x16x32_bf16(af[mi], bf, acc[mi][nj], 0, 0, 0);
            }
        }
    }
    // epilogue: interleaved store — row stride 512 shorts; slot 2*d = -e, 2*d+1 = a
    #pragma unroll
    for (int nj = 0; nj < 4; ++nj) {
        int col = cb * 128 + wc * 64 + nj * 16 + (l & 15);
        bool is_e = (cb < 2);
        float bias = is_e ? b_er[col] : b_ad[col - 256];
        #pragma unroll
        for (int mi = 0; mi < 4; ++mi) {
            #pragma unroll
            for (int reg = 0; reg < 4; ++reg) {
                int rl = row0 + wr * 64 + mi * 16 + (l >> 4) * 4 + reg;
                float x = acc[mi][nj][reg] + bias;
                float y = is_e ? -fast_sigmoid(x) : fast_tanh(x);
                int idx = is_e ? (2 * col) : (2 * (col - 256) + 1);
                ea16[(size_t)rl * 512 + idx] = f2bf(y);
            }
        }
    }
}

// ---------------------------------------------------------------- k3: sequential read/update
// grid = 4*BB blocks; XCD-affine decode: b = bid&255, dq = bid>>8 (the 4 blocks
// of batch b share an XCD under round-robin -> w fetched once per b per XCD).
// 512 thr = 8 mq-waves x 16 m; lane = d. w: scalar s_load depth-4 (wA..wD),
// clamps on scalar pipe. ea: double-buffered batch-of-8 VGPR prefetch (uA/uB) —
// next batch's loads issue a full 8-step window early; batch-level addressing.
__global__ __launch_bounds__(512, 8) void k3_seq(const float* __restrict__ w_buf,
                                                 const unsigned short* __restrict__ ea16,
                                                 const float* __restrict__ init_mem,
                                                 float* __restrict__ state,
                                                 unsigned short* __restrict__ reads16,
                                                 int TC, int first, int last) {
    __shared__ float rdlds[8][8][64];
    int tid = threadIdx.x;
    int mq = tid >> 6, lane = tid & 63;
    int b  = blockIdx.x & (BB - 1);
    int dq = blockIdx.x >> 8;
    int d  = dq * 64 + lane;
    int m0 = mq * 16;
    f32x2 mem[8];
    if (first) {
        #pragma unroll
        for (int i = 0; i < 8; ++i) {
            mem[i].x = init_mem[(size_t)(m0 + 2 * i) * DVv + d];
            mem[i].y = init_mem[(size_t)(m0 + 2 * i + 1) * DVv + d];
        }
    } else {
        #pragma unroll
        for (int i = 0; i < 8; ++i)
            mem[i] = *reinterpret_cast<const f32x2*>(&state[((size_t)b * DVv + d) * MM + m0 + 2 * i]);
    }
    size_t rb = (size_t)b * TC;
    const unsigned* ea32 = reinterpret_cast<const unsigned*>(ea16);
    unsigned wrow = (unsigned)__builtin_amdgcn_readfirstlane((int)((unsigned)(rb * MM) + m0));
    const f32x2* wbase2 = reinterpret_cast<const f32x2*>(w_buf + wrow);
    int tcl = TC - 1;

    f32x2 wA[8], wB[8], wC[8], wD[8];
    #define WLOAD(W, T)                                                             \
    {                                                                               \
        _Pragma("unroll")                                                           \
        for (int j = 0; j < 8; ++j) W[j] = wbase2[(size_t)(T) * 64 + j];            \
    }
    WLOAD(wA, 0) WLOAD(wB, 1) WLOAD(wC, 2) WLOAD(wD, 3)

    unsigned uA[8], uB[8];
    {   // prologue: ea batch 0
        const unsigned* ep = ea32 + rb * 256 + d;
        #pragma unroll
        for (int g = 0; g < 8; ++g) uA[g] = ep[(size_t)g * 256];
    }

    #define K3_STEP(T0, G, UC, WCUR)                                                      \
    {                                                                                     \
        f32x2 EA;                                                                         \
        EA.x = __uint_as_float(UC[G] << 16);            /* -e */                          \
        EA.y = __uint_as_float(UC[G] & 0xffff0000u);    /*  a */                          \
        f32x2 rd; rd.x = 0.f; rd.y = 0.f;                                                 \
        _Pragma("unroll")                                                                 \
        for (int i = 0; i < 8; ++i) {                                                     \
            f32x2 tt;                                                                     \
            asm("v_pk_fma_f32 %0, %1, %2, %0" : "+v"(rd) : "s"(WCUR[i]), "v"(mem[i]));    \
            asm("v_pk_fma_f32 %0, %1, %2, %1 op_sel:[0,0,1] op_sel_hi:[0,1,1]"            \
                : "=v"(tt) : "v"(EA), "v"(mem[i]));                                       \
            asm("v_pk_fma_f32 %0, %1, %2, %0" : "+v"(mem[i]) : "s"(WCUR[i]), "v"(tt));    \
        }                                                                                 \
        rdlds[G][mq][lane] = rd.x + rd.y;                                                 \
        int tp = (T0) + G + 4; tp = (tp < tcl) ? tp : tcl;                                \
        WLOAD(WCUR, tp)                                                                   \
    }
    #define K3_COMBINE(T0)                                                                \
    {                                                                                     \
        __syncthreads();                                                                  \
        int g = tid >> 6, dl = tid & 63;                                                  \
        float s = rdlds[g][0][dl] + rdlds[g][1][dl] + rdlds[g][2][dl] + rdlds[g][3][dl]   \
                + rdlds[g][4][dl] + rdlds[g][5][dl] + rdlds[g][6][dl] + rdlds[g][7][dl];  \
        reads16[(rb + (T0) + g) * DVv + dq * 64 + dl] = f2bf(s);                          \
        __syncthreads();                                                                  \
    }

    for (int t0 = 0; t0 < TC; t0 += 16) {
        {   // issue ea batch t0+8 into uB (full window ahead of its use)
            const unsigned* ep = ea32 + (rb + t0 + 8) * 256 + d;
            #pragma unroll
            for (int g = 0; g < 8; ++g) uB[g] = ep[(size_t)g * 256];
        }
        K3_STEP(t0, 0, uA, wA) K3_STEP(t0, 1, uA, wB) K3_STEP(t0, 2, uA, wC) K3_STEP(t0, 3, uA, wD)
        K3_STEP(t0, 4, uA, wA) K3_STEP(t0, 5, uA, wB) K3_STEP(t0, 6, uA, wC) K3_STEP(t0, 7, uA, wD)
        K3_COMBINE(t0)
        {   // issue ea batch t0+16 into uA (reload current batch if at tail — harmless)
            int nb = (t0 + 16 < TC) ? (t0 + 16) : t0;
            const unsigned* ep = ea32 + (rb + nb) * 256 + d;
            #pragma unroll
            for (int g = 0; g < 8; ++g) uA[g] = ep[(size_t)g * 256];
        }
        int t1 = t0 + 8;
        K3_STEP(t1, 0, uB, wA) K3_STEP(t1, 1, uB, wB) K3_STEP(t1, 2, uB, wC) K3_STEP(t1, 3, uB, wD)
        K3_STEP(t1, 4, uB, wA) K3_STEP(t1, 5, uB, wB) K3_STEP(t1, 6, uB, wC) K3_STEP(t1, 7, uB, wD)
        K3_COMBINE(t1)
    }
    #undef K3_STEP
    #undef K3_COMBINE
    #undef WLOAD
    if (!last) {
        #pragma unroll
        for (int i = 0; i < 8; ++i)
            *reinterpret_cast<f32x2*>(&state[((size_t)b * DVv + d) * MM + m0 + 2 * i]) = mem[i];
    }
}

// ---------------------------------------------------------------- k4: logits via bf16 MFMA
__global__ __launch_bounds__(256) void k4_mfma(const int* __restrict__ q_data,
                                               const unsigned short* __restrict__ q16,
                                               const unsigned short* __restrict__ reads16,
                                               const unsigned short* __restrict__ wrd16,
                                               const float* __restrict__ b_rd,
                                               const float* __restrict__ W_pr,
                                               const float* __restrict__ b_pr,
                                               float* __restrict__ out,
                                               int tcs, int tcm, int coff) {
    __shared__ __align__(16) unsigned short A_lds[128 * 64];
    __shared__ int qidx[128];
    __shared__ float plds[2][128];
    int t = threadIdx.x;
    int row0 = blockIdx.x * 128;
    if (t < 128) {
        int rl = row0 + t;
        qidx[t] = q_data[(rl >> tcs) * SS + coff + (rl & tcm)];
    }
    int l = t & 63;
    int wid = t >> 6, wr = wid >> 1, wc = wid & 1;
    f32x4 acc[4][4];
    #pragma unroll
    for (int i = 0; i < 4; ++i)
        #pragma unroll
        for (int j = 0; j < 4; ++j)
            acc[i][j] = (f32x4){0.f, 0.f, 0.f, 0.f};

    for (int ks = 0; ks < 384; ks += 64) {
        __syncthreads();
        #pragma unroll
        for (int p = 0; p < 4; ++p) {
            int U = p * 256 + t;
            int r = U >> 3, kb = U & 7;
            int kb_log = kb ^ (r & 7);
            int kg = ks + kb_log * 8;
            const unsigned short* src = (kg < 256)
                ? (reads16 + (size_t)(row0 + r) * DVv + kg)
                : (q16 + (size_t)qidx[r] * DKk + (kg - 256));
            int4 v = *reinterpret_cast<const int4*>(src);
            *reinterpret_cast<int4*>(&A_lds[U * 8]) = v;
        }
        __syncthreads();
        #pragma unroll
        for (int ksub = 0; ksub < 2; ++ksub) {
            bf16x8 af[4];
            #pragma unroll
            for (int mi = 0; mi < 4; ++mi) {
                int r = wr * 64 + mi * 16 + (l & 15);
                int kb_log = ksub * 4 + (l >> 4);
                int pu = r * 8 + (kb_log ^ (r & 7));
                af[mi] = *reinterpret_cast<const bf16x8*>(&A_lds[pu * 8]);
            }
            #pragma unroll
            for (int nj = 0; nj < 4; ++nj) {
                int col = wc * 64 + nj * 16 + (l & 15);
                bf16x8 bf = *reinterpret_cast<const bf16x8*>(
                    wrd16 + (size_t)col * 384 + ks + ksub * 32 + (l >> 4) * 8);
                #pragma unroll
                for (int mi = 0; mi < 4; ++mi)
                    acc[mi][nj] = __builtin_amdgcn_mfma_f32_16x16x32_bf16(af[mi], bf, acc[mi][nj], 0, 0, 0);
            }
        }
    }
    float part[16];
    #pragma unroll
    for (int k = 0; k < 16; ++k) part[k] = 0.f;
    #pragma unroll
    for (int nj = 0; nj < 4; ++nj) {
        int col = wc * 64 + nj * 16 + (l & 15);
        float bias = b_rd[col];
        float wpr = W_pr[col];
        #pragma unroll
        for (int mi = 0; mi < 4; ++mi) {
            #pragma unroll
            for (int reg = 0; reg < 4; ++reg) {
                float h = fast_tanh(acc[mi][nj][reg] + bias);
                part[mi * 4 + reg] = fmaf(h, wpr, part[mi * 4 + reg]);
            }
        }
    }
    #pragma unroll
    for (int k = 0; k < 16; ++k) {
        #pragma unroll
        for (int off = 1; off < 16; off <<= 1)
            part[k] += __shfl_xor(part[k], off, 64);
    }
    if ((l & 15) == 0) {
        #pragma unroll
        for (int mi = 0; mi < 4; ++mi)
            #pragma unroll
            for (int reg = 0; reg < 4; ++reg) {
                int row = wr * 64 + mi * 16 + (l >> 4) * 4 + reg;
                plds[wc][row] = part[mi * 4 + reg];
            }
    }
    __syncthreads();
    if (t < 128) {
        float s = plds[0][t] + plds[1][t] + b_pr[0];
        int rl = row0 + t;
        out[(rl >> tcs) * SS + coff + (rl & tcm)] = s;
    }
}

// ---------------------------------------------------------------- launch
extern "C" void kernel_launch(void* const* d_in, const int* in_sizes, int n_in,
                              void* d_out, int out_size, void* d_ws, size_t ws_size,
                              hipStream_t stream) {
    const int*   q_data   = (const int*)d_in[0];
    const int*   qa_data  = (const int*)d_in[1];
    const float* q_tab    = (const float*)d_in[2];
    const float* qa_tab   = (const float*)d_in[3];
    const float* mk       = (const float*)d_in[4];
    const float* init_mem = (const float*)d_in[5];
    const float* W_er     = (const float*)d_in[6];
    const float* b_er     = (const float*)d_in[7];
    const float* W_ad     = (const float*)d_in[8];
    const float* b_ad     = (const float*)d_in[9];
    const float* W_rd     = (const float*)d_in[10];
    const float* b_rd     = (const float*)d_in[11];
    const float* W_pr     = (const float*)d_in[12];
    const float* b_pr     = (const float*)d_in[13];
    float* out = (float*)d_out;

    const size_t state_f = (size_t)BB * MM * DVv;          // 8,388,608 floats
    const size_t qa16_n  = (size_t)in_sizes[3];            // 20001*256 ushorts
    const size_t q16_n   = (size_t)in_sizes[2];            // 10001*128 ushorts
    const size_t wea16_n = 131072;
    const size_t wrd16_n = 49152;
    const size_t mk16_n  = 16384;
    const size_t bf16_f  = (qa16_n + q16_n + wea16_n + wrd16_n + mk16_n) / 2 + 32;

    size_t avail_f = ws_size / 4;
    int TC = 16;
    {
        const int cand[] = {256, 128, 64, 32, 16};
        for (int i = 0; i < 5; ++i) {
            size_t need = state_f + bf16_f + (size_t)BB * cand[i] * (MM + 256 + 128);
            if (need <= avail_f) { TC = cand[i]; break; }
        }
    }
    int NC = SS / TC;
    int tcs = __builtin_ctz(TC);
    int tcm = TC - 1;

    float* ws      = (float*)d_ws;
    float* state   = ws;
    float* w_buf   = state + state_f;                          // B*TC*128 f32
    unsigned short* ea16    = (unsigned short*)(w_buf + (size_t)BB * TC * MM);   // B*TC*512 us
    unsigned short* reads16 = ea16 + (size_t)BB * TC * 512;                      // B*TC*256 us
    unsigned short* qa16  = reads16 + (size_t)BB * TC * DVv;
    unsigned short* q16   = qa16 + qa16_n;
    unsigned short* wea16 = q16 + q16_n;
    unsigned short* wrd16 = wea16 + wea16_n;
    unsigned short* mk16  = wrd16 + wrd16_n;

    kcvt<<<1024, 256, 0, stream>>>(qa_tab, q_tab, W_er, W_ad, W_rd, mk,
                                   qa16, q16, wea16, wrd16, mk16,
                                   (int)qa16_n, (int)q16_n);
    for (int c = 0; c < NC; ++c) {
        int coff = c * TC;
        int rows = BB * TC;
        // k2 first, then k1 (so w_buf is freshly written / L2-warm when k3 reads it)
        k2_ea_mfma<<<(rows / 128) * 4, 256, 0, stream>>>(qa_data, qa16, wea16, b_er, b_ad,
                                                         ea16, tcs, tcm, coff);
        k1_mfma<<<rows / 128, 256, 0, stream>>>(q_data, q16, mk16, w_buf, tcs, tcm, coff);
        k3_seq<<<4 * BB, 512, 0, stream>>>(w_buf, ea16, init_mem, state, reads16,
                                           TC, c == 0, c == NC - 1);
        k4_mfma<<<rows / 128, 256, 0, stream>>>(q_data, q16, reads16, wrd16, b_rd, W_pr, b_pr,
                                                out, tcs, tcm, coff);
    }
}

// Round 14
// 511.073 us; speedup vs baseline: 1.1282x; 1.0988x over previous
//
#include <hip/hip_runtime.h>
#include <hip/hip_bf16.h>

// DKVMN forward. B=256 S=512 M=128 DK=128 DV=256 FC=128.
// Chunked over time (TC=512 single-chunk if ws allows, else 256). Per chunk:
//   k2 (bf16 MFMA): {-e|a} = act(qa @ [We|Wa]^T), 128x512 tile/block (A staged
//       once), stored INTERLEAVED bf16x2 per d
//   k1 (bf16 MFMA): w = softmax(qe @ MK^T)
//   k3: sequential read/update (R11-proven structure): 4*BB blocks x 512 thr
//       (8 mq-waves, 16 m each); w via scalar s_load depth-4 SGPR pipeline;
//       ea batch-8 VGPR prefetch; op_sel gate-fma; G=8 LDS combine.
//   k4 (bf16 MFMA): logits = Wp @ tanh(Wr @ [read|qe])

#define BB    256
#define SS    512
#define MM    128
#define DKk   128
#define DVv   256

typedef float  f32x2  __attribute__((ext_vector_type(2)));
typedef float  f32x4  __attribute__((ext_vector_type(4)));
typedef short  bf16x8 __attribute__((ext_vector_type(8)));

static __device__ __forceinline__ unsigned short f2bf(float f) {
    unsigned u = __float_as_uint(f);
    unsigned r = (u + 0x7FFFu + ((u >> 16) & 1u)) >> 16;
    return (unsigned short)r;
}
static __device__ __forceinline__ float fast_tanh(float x) {
    float ex = __expf(2.f * x);
    return 1.f - 2.f / (ex + 1.f);
}
static __device__ __forceinline__ float fast_sigmoid(float x) {
    return 1.f / (1.f + __expf(-x));
}

// ---------------------------------------------------------------- convert tables to bf16
__global__ __launch_bounds__(256) void kcvt(const float* __restrict__ qa_tab,
                                            const float* __restrict__ q_tab,
                                            const float* __restrict__ W_er,
                                            const float* __restrict__ W_ad,
                                            const float* __restrict__ W_rd,
                                            const float* __restrict__ mk,
                                            unsigned short* __restrict__ qa16,
                                            unsigned short* __restrict__ q16,
                                            unsigned short* __restrict__ wea16,
                                            unsigned short* __restrict__ wrd16,
                                            unsigned short* __restrict__ mk16,
                                            int n_qa, int n_q) {
    for (int i = blockIdx.x * 256 + threadIdx.x; i < n_qa; i += gridDim.x * 256)
        qa16[i] = f2bf(qa_tab[i]);
    for (int i = blockIdx.x * 256 + threadIdx.x; i < n_q; i += gridDim.x * 256)
        q16[i] = f2bf(q_tab[i]);
    for (int i = blockIdx.x * 256 + threadIdx.x; i < 65536; i += gridDim.x * 256) {
        wea16[i] = f2bf(W_er[i]);
        wea16[65536 + i] = f2bf(W_ad[i]);
    }
    for (int i = blockIdx.x * 256 + threadIdx.x; i < 49152; i += gridDim.x * 256)
        wrd16[i] = f2bf(W_rd[i]);
    for (int i = blockIdx.x * 256 + threadIdx.x; i < 16384; i += gridDim.x * 256)
        mk16[i] = f2bf(mk[i]);
}

// ---------------------------------------------------------------- k1: w = softmax(qe @ MK^T) via bf16 MFMA
__global__ __launch_bounds__(256) void k1_mfma(const int* __restrict__ q_data,
                                               const unsigned short* __restrict__ q16,
                                               const unsigned short* __restrict__ mk16,
                                               float* __restrict__ w_buf,
                                               int tcs, int tcm, int coff) {
    __shared__ __align__(16) unsigned short A_lds[128 * 64];
    __shared__ int qidx[128];
    int t = threadIdx.x;
    int row0 = blockIdx.x * 128;
    if (t < 128) {
        int rl = row0 + t;
        qidx[t] = q_data[(rl >> tcs) * SS + coff + (rl & tcm)];
    }
    int l = t & 63;
    int wid = t >> 6;
    f32x4 acc[2][8];
    #pragma unroll
    for (int i = 0; i < 2; ++i)
        #pragma unroll
        for (int j = 0; j < 8; ++j)
            acc[i][j] = (f32x4){0.f, 0.f, 0.f, 0.f};

    for (int ks = 0; ks < 128; ks += 64) {
        __syncthreads();
        #pragma unroll
        for (int p = 0; p < 4; ++p) {
            int U = p * 256 + t;
            int r = U >> 3, kb = U & 7;
            int kb_log = kb ^ (r & 7);
            int4 v = *reinterpret_cast<const int4*>(q16 + (size_t)qidx[r] * DKk + ks + kb_log * 8);
            *reinterpret_cast<int4*>(&A_lds[U * 8]) = v;
        }
        __syncthreads();
        #pragma unroll
        for (int ksub = 0; ksub < 2; ++ksub) {
            bf16x8 af[2];
            #pragma unroll
            for (int mi = 0; mi < 2; ++mi) {
                int r = wid * 32 + mi * 16 + (l & 15);
                int kb_log = ksub * 4 + (l >> 4);
                int pu = r * 8 + (kb_log ^ (r & 7));
                af[mi] = *reinterpret_cast<const bf16x8*>(&A_lds[pu * 8]);
            }
            #pragma unroll
            for (int nj = 0; nj < 8; ++nj) {
                int col = nj * 16 + (l & 15);
                bf16x8 bf = *reinterpret_cast<const bf16x8*>(
                    mk16 + (size_t)col * DKk + ks + ksub * 32 + (l >> 4) * 8);
                #pragma unroll
                for (int mi = 0; mi < 2; ++mi)
                    acc[mi][nj] = __builtin_amdgcn_mfma_f32_16x16x32_bf16(af[mi], bf, acc[mi][nj], 0, 0, 0);
            }
        }
    }
    #pragma unroll
    for (int mi = 0; mi < 2; ++mi) {
        #pragma unroll
        for (int reg = 0; reg < 4; ++reg) {
            float mx = acc[mi][0][reg];
            #pragma unroll
            for (int nj = 1; nj < 8; ++nj) mx = fmaxf(mx, acc[mi][nj][reg]);
            #pragma unroll
            for (int off = 1; off < 16; off <<= 1) mx = fmaxf(mx, __shfl_xor(mx, off, 64));
            float p[8], s = 0.f;
            #pragma unroll
            for (int nj = 0; nj < 8; ++nj) { p[nj] = __expf(acc[mi][nj][reg] - mx); s += p[nj]; }
            #pragma unroll
            for (int off = 1; off < 16; off <<= 1) s += __shfl_xor(s, off, 64);
            float inv = 1.f / s;
            int row = row0 + wid * 32 + mi * 16 + (l >> 4) * 4 + reg;
            #pragma unroll
            for (int nj = 0; nj < 8; ++nj)
                w_buf[(size_t)row * MM + nj * 16 + (l & 15)] = p[nj] * inv;
        }
    }
}

// ---------------------------------------------------------------- k2: {-e|a} via bf16 MFMA, 128x512 tile (A staged once)
__global__ __launch_bounds__(512) void k2_ea_mfma(const int* __restrict__ qa_data,
                                                  const unsigned short* __restrict__ qa16,
                                                  const unsigned short* __restrict__ wea16,
                                                  const float* __restrict__ b_er,
                                                  const float* __restrict__ b_ad,
                                                  unsigned short* __restrict__ ea16,
                                                  int tcs, int tcm, int coff) {
    __shared__ __align__(16) unsigned short A_lds[128 * 64];
    __shared__ int qidx[128];
    int t = threadIdx.x;
    int row0 = blockIdx.x * 128;
    if (t < 128) {
        int rl = row0 + t;
        qidx[t] = qa_data[(rl >> tcs) * SS + coff + (rl & tcm)];
    }
    int l = t & 63;
    int wid = t >> 6, wr = wid >> 2, wc = wid & 3;   // wave = 64 rows x 128 cols
    f32x4 acc[4][8];
    #pragma unroll
    for (int i = 0; i < 4; ++i)
        #pragma unroll
        for (int j = 0; j < 8; ++j)
            acc[i][j] = (f32x4){0.f, 0.f, 0.f, 0.f};

    for (int ks = 0; ks < 256; ks += 64) {
        __syncthreads();
        #pragma unroll
        for (int p = 0; p < 2; ++p) {
            int U = p * 512 + t;
            int r = U >> 3, kb = U & 7;
            int kb_log = kb ^ (r & 7);
            int4 v = *reinterpret_cast<const int4*>(qa16 + (size_t)qidx[r] * 256 + ks + kb_log * 8);
            *reinterpret_cast<int4*>(&A_lds[U * 8]) = v;
        }
        __syncthreads();
        #pragma unroll
        for (int ksub = 0; ksub < 2; ++ksub) {
            bf16x8 af[4];
            #pragma unroll
            for (int mi = 0; mi < 4; ++mi) {
                int r = wr * 64 + mi * 16 + (l & 15);
                int kb_log = ksub * 4 + (l >> 4);
                int pu = r * 8 + (kb_log ^ (r & 7));
                af[mi] = *reinterpret_cast<const bf16x8*>(&A_lds[pu * 8]);
            }
            #pragma unroll
            for (int nj = 0; nj < 8; ++nj) {
                int col = wc * 128 + nj * 16 + (l & 15);   // 0..511 over stacked [We;Wa]
                bf16x8 bf = *reinterpret_cast<const bf16x8*>(
                    wea16 + (size_t)col * 256 + ks + ksub * 32 + (l >> 4) * 8);
                #pragma unroll
                for (int mi = 0; mi < 4; ++mi)
                    acc[mi][nj] = __builtin_amdgcn_mfma_f32_16x16x32_bf16(af[mi], bf, acc[mi][nj], 0, 0, 0);
            }
        }
    }
    // epilogue: interleaved store — row stride 512 shorts; slot 2*d = -e, 2*d+1 = a
    #pragma unroll
    for (int nj = 0; nj < 8; ++nj) {
        int col = wc * 128 + nj * 16 + (l & 15);
        bool is_e = (col < 256);
        float bias = is_e ? b_er[col] : b_ad[col - 256];
        int idx = is_e ? (2 * col) : (2 * (col - 256) + 1);
        #pragma unroll
        for (int mi = 0; mi < 4; ++mi) {
            #pragma unroll
            for (int reg = 0; reg < 4; ++reg) {
                int rl = row0 + wr * 64 + mi * 16 + (l >> 4) * 4 + reg;
                float x = acc[mi][nj][reg] + bias;
                float y = is_e ? -fast_sigmoid(x) : fast_tanh(x);
                ea16[(size_t)rl * 512 + idx] = f2bf(y);
            }
        }
    }
}

// ---------------------------------------------------------------- k3: sequential read/update (R11-proven)
// grid = 4*BB blocks (b = bid>>2, dq = bid&3) x 512 thr = 8 mq-waves x 16 m;
// lane = d. w: scalar s_load depth-4 (wA..wD). ea: batch-8 VGPR prefetch.
// op_sel gate-fma. G=8 LDS combine, 2 barriers per 8 steps.
__global__ __launch_bounds__(512, 8) void k3_seq(const float* __restrict__ w_buf,
                                                 const unsigned short* __restrict__ ea16,
                                                 const float* __restrict__ init_mem,
                                                 float* __restrict__ state,
                                                 unsigned short* __restrict__ reads16,
                                                 int TC, int first, int last) {
    __shared__ float rdlds[8][8][64];
    int tid = threadIdx.x;
    int mq = tid >> 6, lane = tid & 63;
    int b  = blockIdx.x >> 2;
    int dq = blockIdx.x & 3;
    int d  = dq * 64 + lane;
    int m0 = mq * 16;
    f32x2 mem[8];
    if (first) {
        #pragma unroll
        for (int i = 0; i < 8; ++i) {
            mem[i].x = init_mem[(size_t)(m0 + 2 * i) * DVv + d];
            mem[i].y = init_mem[(size_t)(m0 + 2 * i + 1) * DVv + d];
        }
    } else {
        #pragma unroll
        for (int i = 0; i < 8; ++i)
            mem[i] = *reinterpret_cast<const f32x2*>(&state[((size_t)b * DVv + d) * MM + m0 + 2 * i]);
    }
    size_t rb = (size_t)b * TC;
    const unsigned* ea32 = reinterpret_cast<const unsigned*>(ea16);
    unsigned wrow = (unsigned)__builtin_amdgcn_readfirstlane((int)((unsigned)(rb * MM) + m0));
    const f32x2* wbase2 = reinterpret_cast<const f32x2*>(w_buf + wrow);
    int tcl = TC - 1;

    f32x2 wA[8], wB[8], wC[8], wD[8];
    #define WLOAD(W, T)                                                             \
    {                                                                               \
        _Pragma("unroll")                                                           \
        for (int j = 0; j < 8; ++j) W[j] = wbase2[(size_t)(T) * 64 + j];            \
    }
    WLOAD(wA, 0) WLOAD(wB, 1) WLOAD(wC, 2) WLOAD(wD, 3)

    for (int t0 = 0; t0 < TC; t0 += 8) {
        // e/a prefetch for 8 steps: one dword {ne_bf16, a_bf16} per step
        unsigned u8[8];
        #pragma unroll
        for (int g = 0; g < 8; ++g)
            u8[g] = ea32[(rb + t0 + g) * 256 + d];
        #define K3_STEP(G, WCUR)                                                              \
        {                                                                                     \
            f32x2 EA;                                                                         \
            EA.x = __uint_as_float(u8[G] << 16);            /* -e */                          \
            EA.y = __uint_as_float(u8[G] & 0xffff0000u);    /*  a */                          \
            f32x2 rd; rd.x = 0.f; rd.y = 0.f;                                                 \
            _Pragma("unroll")                                                                 \
            for (int i = 0; i < 8; ++i) {                                                     \
                f32x2 tt;                                                                     \
                asm("v_pk_fma_f32 %0, %1, %2, %0" : "+v"(rd) : "s"(WCUR[i]), "v"(mem[i]));    \
                asm("v_pk_fma_f32 %0, %1, %2, %1 op_sel:[0,0,1] op_sel_hi:[0,1,1]"            \
                    : "=v"(tt) : "v"(EA), "v"(mem[i]));                                       \
                asm("v_pk_fma_f32 %0, %1, %2, %0" : "+v"(mem[i]) : "s"(WCUR[i]), "v"(tt));    \
            }                                                                                 \
            rdlds[G][mq][lane] = rd.x + rd.y;                                                 \
            int tp = t0 + G + 4; tp = (tp < tcl) ? tp : tcl;                                  \
            WLOAD(WCUR, tp)                                                                   \
        }
        K3_STEP(0, wA) K3_STEP(1, wB) K3_STEP(2, wC) K3_STEP(3, wD)
        K3_STEP(4, wA) K3_STEP(5, wB) K3_STEP(6, wC) K3_STEP(7, wD)
        #undef K3_STEP
        __syncthreads();
        {
            int g = tid >> 6, dl = tid & 63;
            float s = rdlds[g][0][dl] + rdlds[g][1][dl] + rdlds[g][2][dl] + rdlds[g][3][dl]
                    + rdlds[g][4][dl] + rdlds[g][5][dl] + rdlds[g][6][dl] + rdlds[g][7][dl];
            reads16[(rb + t0 + g) * DVv + dq * 64 + dl] = f2bf(s);
        }
        __syncthreads();
    }
    #undef WLOAD
    if (!last) {
        #pragma unroll
        for (int i = 0; i < 8; ++i)
            *reinterpret_cast<f32x2*>(&state[((size_t)b * DVv + d) * MM + m0 + 2 * i]) = mem[i];
    }
}

// ---------------------------------------------------------------- k4: logits via bf16 MFMA
__global__ __launch_bounds__(256) void k4_mfma(const int* __restrict__ q_data,
                                               const unsigned short* __restrict__ q16,
                                               const unsigned short* __restrict__ reads16,
                                               const unsigned short* __restrict__ wrd16,
                                               const float* __restrict__ b_rd,
                                               const float* __restrict__ W_pr,
                                               const float* __restrict__ b_pr,
                                               float* __restrict__ out,
                                               int tcs, int tcm, int coff) {
    __shared__ __align__(16) unsigned short A_lds[128 * 64];
    __shared__ int qidx[128];
    __shared__ float plds[2][128];
    int t = threadIdx.x;
    int row0 = blockIdx.x * 128;
    if (t < 128) {
        int rl = row0 + t;
        qidx[t] = q_data[(rl >> tcs) * SS + coff + (rl & tcm)];
    }
    int l = t & 63;
    int wid = t >> 6, wr = wid >> 1, wc = wid & 1;
    f32x4 acc[4][4];
    #pragma unroll
    for (int i = 0; i < 4; ++i)
        #pragma unroll
        for (int j = 0; j < 4; ++j)
            acc[i][j] = (f32x4){0.f, 0.f, 0.f, 0.f};

    for (int ks = 0; ks < 384; ks += 64) {
        __syncthreads();
        #pragma unroll
        for (int p = 0; p < 4; ++p) {
            int U = p * 256 + t;
            int r = U >> 3, kb = U & 7;
            int kb_log = kb ^ (r & 7);
            int kg = ks + kb_log * 8;
            const unsigned short* src = (kg < 256)
                ? (reads16 + (size_t)(row0 + r) * DVv + kg)
                : (q16 + (size_t)qidx[r] * DKk + (kg - 256));
            int4 v = *reinterpret_cast<const int4*>(src);
            *reinterpret_cast<int4*>(&A_lds[U * 8]) = v;
        }
        __syncthreads();
        #pragma unroll
        for (int ksub = 0; ksub < 2; ++ksub) {
            bf16x8 af[4];
            #pragma unroll
            for (int mi = 0; mi < 4; ++mi) {
                int r = wr * 64 + mi * 16 + (l & 15);
                int kb_log = ksub * 4 + (l >> 4);
                int pu = r * 8 + (kb_log ^ (r & 7));
                af[mi] = *reinterpret_cast<const bf16x8*>(&A_lds[pu * 8]);
            }
            #pragma unroll
            for (int nj = 0; nj < 4; ++nj) {
                int col = wc * 64 + nj * 16 + (l & 15);
                bf16x8 bf = *reinterpret_cast<const bf16x8*>(
                    wrd16 + (size_t)col * 384 + ks + ksub * 32 + (l >> 4) * 8);
                #pragma unroll
                for (int mi = 0; mi < 4; ++mi)
                    acc[mi][nj] = __builtin_amdgcn_mfma_f32_16x16x32_bf16(af[mi], bf, acc[mi][nj], 0, 0, 0);
            }
        }
    }
    float part[16];
    #pragma unroll
    for (int k = 0; k < 16; ++k) part[k] = 0.f;
    #pragma unroll
    for (int nj = 0; nj < 4; ++nj) {
        int col = wc * 64 + nj * 16 + (l & 15);
        float bias = b_rd[col];
        float wpr = W_pr[col];
        #pragma unroll
        for (int mi = 0; mi < 4; ++mi) {
            #pragma unroll
            for (int reg = 0; reg < 4; ++reg) {
                float h = fast_tanh(acc[mi][nj][reg] + bias);
                part[mi * 4 + reg] = fmaf(h, wpr, part[mi * 4 + reg]);
            }
        }
    }
    #pragma unroll
    for (int k = 0; k < 16; ++k) {
        #pragma unroll
        for (int off = 1; off < 16; off <<= 1)
            part[k] += __shfl_xor(part[k], off, 64);
    }
    if ((l & 15) == 0) {
        #pragma unroll
        for (int mi = 0; mi < 4; ++mi)
            #pragma unroll
            for (int reg = 0; reg < 4; ++reg) {
                int row = wr * 64 + mi * 16 + (l >> 4) * 4 + reg;
                plds[wc][row] = part[mi * 4 + reg];
            }
    }
    __syncthreads();
    if (t < 128) {
        float s = plds[0][t] + plds[1][t] + b_pr[0];
        int rl = row0 + t;
        out[(rl >> tcs) * SS + coff + (rl & tcm)] = s;
    }
}

// ---------------------------------------------------------------- launch
extern "C" void kernel_launch(void* const* d_in, const int* in_sizes, int n_in,
                              void* d_out, int out_size, void* d_ws, size_t ws_size,
                              hipStream_t stream) {
    const int*   q_data   = (const int*)d_in[0];
    const int*   qa_data  = (const int*)d_in[1];
    const float* q_tab    = (const float*)d_in[2];
    const float* qa_tab   = (const float*)d_in[3];
    const float* mk       = (const float*)d_in[4];
    const float* init_mem = (const float*)d_in[5];
    const float* W_er     = (const float*)d_in[6];
    const float* b_er     = (const float*)d_in[7];
    const float* W_ad     = (const float*)d_in[8];
    const float* b_ad     = (const float*)d_in[9];
    const float* W_rd     = (const float*)d_in[10];
    const float* b_rd     = (const float*)d_in[11];
    const float* W_pr     = (const float*)d_in[12];
    const float* b_pr     = (const float*)d_in[13];
    float* out = (float*)d_out;

    const size_t state_f = (size_t)BB * MM * DVv;          // 8,388,608 floats
    const size_t qa16_n  = (size_t)in_sizes[3];            // 20001*256 ushorts
    const size_t q16_n   = (size_t)in_sizes[2];            // 10001*128 ushorts
    const size_t wea16_n = 131072;
    const size_t wrd16_n = 49152;
    const size_t mk16_n  = 16384;
    const size_t bf16_f  = (qa16_n + q16_n + wea16_n + wrd16_n + mk16_n) / 2 + 32;

    size_t avail_f = ws_size / 4;
    int TC = 16;
    {
        const int cand[] = {512, 256, 128, 64, 32, 16};
        for (int i = 0; i < 6; ++i) {
            int nc = SS / cand[i];
            size_t need = (nc > 1 ? state_f : 0) + bf16_f
                        + (size_t)BB * cand[i] * (MM + 256 + 128);
            if (need <= avail_f) { TC = cand[i]; break; }
        }
    }
    int NC = SS / TC;
    int tcs = __builtin_ctz(TC);
    int tcm = TC - 1;

    float* ws      = (float*)d_ws;
    float* state   = ws;                                       // unused when NC==1
    float* w_buf   = state + (NC > 1 ? state_f : 0);           // B*TC*128 f32
    unsigned short* ea16    = (unsigned short*)(w_buf + (size_t)BB * TC * MM);   // B*TC*512 us
    unsigned short* reads16 = ea16 + (size_t)BB * TC * 512;                      // B*TC*256 us
    unsigned short* qa16  = reads16 + (size_t)BB * TC * DVv;
    unsigned short* q16   = qa16 + qa16_n;
    unsigned short* wea16 = q16 + q16_n;
    unsigned short* wrd16 = wea16 + wea16_n;
    unsigned short* mk16  = wrd16 + wrd16_n;

    kcvt<<<1024, 256, 0, stream>>>(qa_tab, q_tab, W_er, W_ad, W_rd, mk,
                                   qa16, q16, wea16, wrd16, mk16,
                                   (int)qa16_n, (int)q16_n);
    for (int c = 0; c < NC; ++c) {
        int coff = c * TC;
        int rows = BB * TC;
        // k2 first, then k1 (so w_buf is freshly written / cache-warm for k3)
        k2_ea_mfma<<<rows / 128, 512, 0, stream>>>(qa_data, qa16, wea16, b_er, b_ad,
                                                   ea16, tcs, tcm, coff);
        k1_mfma<<<rows / 128, 256, 0, stream>>>(q_data, q16, mk16, w_buf, tcs, tcm, coff);
        k3_seq<<<4 * BB, 512, 0, stream>>>(w_buf, ea16, init_mem, state, reads16,
                                           TC, c == 0, c == NC - 1);
        k4_mfma<<<rows / 128, 256, 0, stream>>>(q_data, q16, reads16, wrd16, b_rd, W_pr, b_pr,
                                                out, tcs, tcm, coff);
    }
}